// Round 1
// baseline (1071.015 us; speedup 1.0000x reference)
//
#include <hip/hip_runtime.h>
#include <hip/hip_bf16.h>

#define EMB 128

// ---------------- CSR build ----------------

__global__ void deg_kernel(const int* __restrict__ dst, int* __restrict__ deg, int E) {
    int e = blockIdx.x * blockDim.x + threadIdx.x;
    if (e < E) atomicAdd(&deg[dst[e]], 1);
}

// exclusive scan, 1024 elems/block (256 thr x 4). Also emits dinv.
__global__ void scan1_kernel(const int* __restrict__ deg, int* __restrict__ rowptr,
                             float* __restrict__ dinv, int* __restrict__ bsum, int N) {
    __shared__ int sc[256];
    int t = threadIdx.x;
    int base = blockIdx.x * 1024 + t * 4;
    int d0 = 0, d1 = 0, d2 = 0, d3 = 0;
    if (base + 3 < N) {
        int4 v = *(const int4*)(deg + base);
        d0 = v.x; d1 = v.y; d2 = v.z; d3 = v.w;
    } else {
        if (base     < N) d0 = deg[base];
        if (base + 1 < N) d1 = deg[base + 1];
        if (base + 2 < N) d2 = deg[base + 2];
        if (base + 3 < N) d3 = deg[base + 3];
    }
    int s = d0 + d1 + d2 + d3;
    sc[t] = s;
    __syncthreads();
    for (int off = 1; off < 256; off <<= 1) {
        int v = (t >= off) ? sc[t - off] : 0;
        __syncthreads();
        sc[t] += v;
        __syncthreads();
    }
    int excl = sc[t] - s;
    if (t == 255) bsum[blockIdx.x] = sc[255];
    int dd[4] = {d0, d1, d2, d3};
    int p = excl;
    #pragma unroll
    for (int j = 0; j < 4; j++) {
        int i = base + j;
        if (i < N) {
            rowptr[i] = p;
            dinv[i] = dd[j] > 0 ? rsqrtf((float)dd[j]) : 0.0f;
        }
        p += dd[j];
    }
}

__global__ void scan2_kernel(int* bsum, int nb) {  // nb <= 128
    __shared__ int sc[128];
    int t = threadIdx.x;
    int v = (t < nb) ? bsum[t] : 0;
    sc[t] = v;
    __syncthreads();
    for (int off = 1; off < 128; off <<= 1) {
        int u = (t >= off) ? sc[t - off] : 0;
        __syncthreads();
        sc[t] += u;
        __syncthreads();
    }
    if (t < nb) bsum[t] = sc[t] - v;  // exclusive
}

__global__ void scan3_kernel(int* __restrict__ rowptr, const int* __restrict__ bsum,
                             int N, int E) {
    int t = threadIdx.x, b = blockIdx.x;
    int add = bsum[b];
    int base = b * 1024 + t * 4;
    #pragma unroll
    for (int j = 0; j < 4; j++) {
        int i = base + j;
        if (i < N) rowptr[i] += add;
    }
    if (b == 0 && t == 0) rowptr[N] = E;
}

__global__ void fill_kernel(const int* __restrict__ src, const int* __restrict__ dst,
                            const int* __restrict__ rowptr, int* __restrict__ cursor,
                            int* __restrict__ csr, int E) {
    int e = blockIdx.x * blockDim.x + threadIdx.x;
    if (e < E) {
        int d = dst[e];
        int p = atomicAdd(&cursor[d], 1);
        csr[rowptr[d] + p] = src[e];
    }
}

// ---------------- aggregation: out[n] = dinv[n] * sum_{s in N(n)} dinv[s]*x[s] ----------------
// one wave per node, float2 per lane (64 lanes x 2 = 128 feats)

__global__ __launch_bounds__(256) void agg_kernel(
    const float* __restrict__ xu, const float* __restrict__ xi, int split,
    const int* __restrict__ rowptr, const int* __restrict__ csr,
    const float* __restrict__ dinv, float* __restrict__ out, int N) {
    int node = blockIdx.x * 4 + (threadIdx.x >> 6);
    int lane = threadIdx.x & 63;
    if (node >= N) return;
    int e0 = rowptr[node], e1 = rowptr[node + 1];
    float ax = 0.0f, ay = 0.0f;
    for (int e = e0; e < e1; e++) {
        int s = csr[e];
        const float* px = (s < split) ? (xu + (size_t)s * EMB)
                                      : (xi + (size_t)(s - split) * EMB);
        float w = dinv[s];
        float2 v = *(const float2*)(px + lane * 2);
        ax += w * v.x;
        ay += w * v.y;
    }
    float wd = dinv[node];
    float2 r;
    r.x = ax * wd;
    r.y = ay * wd;
    *(float2*)(out + (size_t)node * EMB + lane * 2) = r;
}

// ---------------- fp32 GEMM + ReLU: out[M,128] = relu(A[M,128] @ W[128,128]) ----------------
// block: 256 thr, tile 64 rows x 128 cols, BK=32; thread tile 4 rows x 8 cols
// (cols c0..c0+3 and 64+c0..64+c0+3 to keep LDS reads 2-way max = free)

__global__ __launch_bounds__(256) void gemm_relu_kernel(
    const float* __restrict__ A, const float* __restrict__ W,
    float* __restrict__ out, int M) {
    __shared__ float As[64][36];   // +4 pad keeps 16B alignment, 2-way banks
    __shared__ float Ws[32][128];
    int t = threadIdx.x;
    int row0 = blockIdx.x * 64;
    int cg = t & 15, rg = t >> 4;
    int c0 = cg * 4;
    float4 acc0[4] = {};
    float4 acc1[4] = {};
    for (int k0 = 0; k0 < 128; k0 += 32) {
        // stage A tile (64x32 = 512 float4, 2 per thread)
        int f = t;
        #pragma unroll
        for (int it = 0; it < 2; it++, f += 256) {
            int r = f >> 3, kk4 = (f & 7) * 4;
            int row = row0 + r;
            float4 v = {0.f, 0.f, 0.f, 0.f};
            if (row < M) v = *(const float4*)(A + (size_t)row * EMB + k0 + kk4);
            *(float4*)&As[r][kk4] = v;
        }
        // stage W tile (32x128 = 1024 float4, 4 per thread)
        int g = t;
        #pragma unroll
        for (int it = 0; it < 4; it++, g += 256) {
            int kk = g >> 5, c4 = (g & 31) * 4;
            *(float4*)&Ws[kk][c4] = *(const float4*)(W + (size_t)(k0 + kk) * EMB + c4);
        }
        __syncthreads();
        #pragma unroll
        for (int kk4 = 0; kk4 < 32; kk4 += 4) {
            float4 a[4];
            #pragma unroll
            for (int r = 0; r < 4; r++) a[r] = *(const float4*)&As[rg * 4 + r][kk4];
            #pragma unroll
            for (int kk = 0; kk < 4; kk++) {
                float4 w0 = *(const float4*)&Ws[kk4 + kk][c0];
                float4 w1 = *(const float4*)&Ws[kk4 + kk][64 + c0];
                #pragma unroll
                for (int r = 0; r < 4; r++) {
                    float av = (kk == 0) ? a[r].x : (kk == 1) ? a[r].y
                             : (kk == 2) ? a[r].z : a[r].w;
                    acc0[r].x += av * w0.x; acc0[r].y += av * w0.y;
                    acc0[r].z += av * w0.z; acc0[r].w += av * w0.w;
                    acc1[r].x += av * w1.x; acc1[r].y += av * w1.y;
                    acc1[r].z += av * w1.z; acc1[r].w += av * w1.w;
                }
            }
        }
        __syncthreads();
    }
    #pragma unroll
    for (int r = 0; r < 4; r++) {
        int row = row0 + rg * 4 + r;
        if (row < M) {
            float4 v0 = acc0[r], v1 = acc1[r];
            v0.x = fmaxf(v0.x, 0.f); v0.y = fmaxf(v0.y, 0.f);
            v0.z = fmaxf(v0.z, 0.f); v0.w = fmaxf(v0.w, 0.f);
            v1.x = fmaxf(v1.x, 0.f); v1.y = fmaxf(v1.y, 0.f);
            v1.z = fmaxf(v1.z, 0.f); v1.w = fmaxf(v1.w, 0.f);
            *(float4*)(out + (size_t)row * EMB + c0) = v0;
            *(float4*)(out + (size_t)row * EMB + 64 + c0) = v1;
        }
    }
}

// ---------------- launch ----------------

extern "C" void kernel_launch(void* const* d_in, const int* in_sizes, int n_in,
                              void* d_out, int out_size, void* d_ws, size_t ws_size,
                              hipStream_t stream) {
    (void)n_in; (void)out_size; (void)ws_size;
    const float* Gu = (const float*)d_in[0];
    const float* Gi = (const float*)d_in[1];
    const float* W0 = (const float*)d_in[2];
    const float* W1 = (const float*)d_in[3];
    const float* W2 = (const float*)d_in[4];
    const int* ei = (const int*)d_in[5];

    int nu = in_sizes[0] / EMB;          // 60000
    int ni = in_sizes[1] / EMB;          // 40000
    int N = nu + ni;                     // 100000
    int E = in_sizes[5] / 2;             // 2000000
    const int* src = ei;
    const int* dst = ei + E;

    // workspace layout (all 16B aligned)
    float* Abuf = (float*)d_ws;                       // N*128 floats = 51.2 MB
    int* deg    = (int*)(Abuf + (size_t)N * EMB);     // N
    int* cursor = deg + N;                            // N (contiguous with deg for one memset)
    int* rowptr = cursor + N;                         // N+1
    float* dinv = (float*)(rowptr + N + 1);           // N
    int* csr    = (int*)(dinv + N);                   // E
    int* bsum   = csr + E;                            // <=128
    float* X    = (float*)d_out;                      // ping buffer + final output

    hipMemsetAsync(deg, 0, sizeof(int) * 2 * (size_t)N, stream);  // deg + cursor

    deg_kernel<<<(E + 255) / 256, 256, 0, stream>>>(dst, deg, E);
    int nb = (N + 1023) / 1024;                       // 98
    scan1_kernel<<<nb, 256, 0, stream>>>(deg, rowptr, dinv, bsum, N);
    scan2_kernel<<<1, 128, 0, stream>>>(bsum, nb);
    scan3_kernel<<<nb, 256, 0, stream>>>(rowptr, bsum, N, E);
    fill_kernel<<<(E + 255) / 256, 256, 0, stream>>>(src, dst, rowptr, cursor, csr, E);

    int aggBlocks = (N + 3) / 4;
    int gemmBlocks = (N + 63) / 64;

    // layer 1: agg over (Gu, Gi), then @W0 + relu -> X
    agg_kernel<<<aggBlocks, 256, 0, stream>>>(Gu, Gi, nu, rowptr, csr, dinv, Abuf, N);
    gemm_relu_kernel<<<gemmBlocks, 256, 0, stream>>>(Abuf, W0, X, N);
    // layer 2
    agg_kernel<<<aggBlocks, 256, 0, stream>>>(X, X + (size_t)nu * EMB, nu, rowptr, csr, dinv, Abuf, N);
    gemm_relu_kernel<<<gemmBlocks, 256, 0, stream>>>(Abuf, W1, X, N);
    // layer 3
    agg_kernel<<<aggBlocks, 256, 0, stream>>>(X, X + (size_t)nu * EMB, nu, rowptr, csr, dinv, Abuf, N);
    gemm_relu_kernel<<<gemmBlocks, 256, 0, stream>>>(Abuf, W2, X, N);
}

// Round 2
// 825.344 us; speedup vs baseline: 1.2977x; 1.2977x over previous
//
#include <hip/hip_runtime.h>
#include <hip/hip_bf16.h>

#define EMB 128

// ---------------- CSR build ----------------

__global__ void deg_kernel(const int* __restrict__ dst, int* __restrict__ deg, int E) {
    int e = blockIdx.x * blockDim.x + threadIdx.x;
    if (e < E) atomicAdd(&deg[dst[e]], 1);
}

// exclusive scan, 1024 elems/block (256 thr x 4). Also emits dinv.
__global__ void scan1_kernel(const int* __restrict__ deg, int* __restrict__ rowptr,
                             float* __restrict__ dinv, int* __restrict__ bsum, int N) {
    __shared__ int sc[256];
    int t = threadIdx.x;
    int base = blockIdx.x * 1024 + t * 4;
    int d0 = 0, d1 = 0, d2 = 0, d3 = 0;
    if (base + 3 < N) {
        int4 v = *(const int4*)(deg + base);
        d0 = v.x; d1 = v.y; d2 = v.z; d3 = v.w;
    } else {
        if (base     < N) d0 = deg[base];
        if (base + 1 < N) d1 = deg[base + 1];
        if (base + 2 < N) d2 = deg[base + 2];
        if (base + 3 < N) d3 = deg[base + 3];
    }
    int s = d0 + d1 + d2 + d3;
    sc[t] = s;
    __syncthreads();
    for (int off = 1; off < 256; off <<= 1) {
        int v = (t >= off) ? sc[t - off] : 0;
        __syncthreads();
        sc[t] += v;
        __syncthreads();
    }
    int excl = sc[t] - s;
    if (t == 255) bsum[blockIdx.x] = sc[255];
    int dd[4] = {d0, d1, d2, d3};
    int p = excl;
    #pragma unroll
    for (int j = 0; j < 4; j++) {
        int i = base + j;
        if (i < N) {
            rowptr[i] = p;
            dinv[i] = dd[j] > 0 ? rsqrtf((float)dd[j]) : 0.0f;
        }
        p += dd[j];
    }
}

__global__ void scan2_kernel(int* bsum, int nb) {  // nb <= 128
    __shared__ int sc[128];
    int t = threadIdx.x;
    int v = (t < nb) ? bsum[t] : 0;
    sc[t] = v;
    __syncthreads();
    for (int off = 1; off < 128; off <<= 1) {
        int u = (t >= off) ? sc[t - off] : 0;
        __syncthreads();
        sc[t] += u;
        __syncthreads();
    }
    if (t < nb) bsum[t] = sc[t] - v;  // exclusive
}

__global__ void scan3_kernel(int* __restrict__ rowptr, const int* __restrict__ bsum,
                             int N, int E) {
    int t = threadIdx.x, b = blockIdx.x;
    int add = bsum[b];
    int base = b * 1024 + t * 4;
    #pragma unroll
    for (int j = 0; j < 4; j++) {
        int i = base + j;
        if (i < N) rowptr[i] += add;
    }
    if (b == 0 && t == 0) rowptr[N] = E;
}

__global__ void fill_kernel(const int* __restrict__ src, const int* __restrict__ dst,
                            const int* __restrict__ rowptr, int* __restrict__ cursor,
                            int* __restrict__ csr, int E) {
    int e = blockIdx.x * blockDim.x + threadIdx.x;
    if (e < E) {
        int d = dst[e];
        int p = atomicAdd(&cursor[d], 1);
        csr[rowptr[d] + p] = src[e];
    }
}

// ---------------- aggregation: out[n] = dinv[n] * sum_{s in N(n)} dinv[s]*x[s] ----------------
// one wave per node, float2 per lane (64 lanes x 2 = 128 feats).
// Lane-parallel index/weight prefetch (1 coalesced csr load per 64 edges),
// then 8 independent 512B row gathers in flight per batch.

__global__ __launch_bounds__(256) void agg_kernel(
    const float* __restrict__ xu, const float* __restrict__ xi, int split,
    const int* __restrict__ rowptr, const int* __restrict__ csr,
    const float* __restrict__ dinv, float* __restrict__ out, int N) {
    int node = blockIdx.x * 4 + (threadIdx.x >> 6);
    int lane = threadIdx.x & 63;
    if (node >= N) return;
    int e0 = rowptr[node], e1 = rowptr[node + 1];
    float ax = 0.0f, ay = 0.0f;
    for (int base = e0; base < e1; base += 64) {
        int n = e1 - base;
        if (n > 64) n = 64;
        // lane-parallel prefetch of indices + weights (pad with w=0)
        int s = 0;
        float w = 0.0f;
        if (lane < n) {
            s = csr[base + lane];
            w = dinv[s];
        }
        int nn = (n + 7) & ~7;
        for (int j = 0; j < nn; j += 8) {
            float2 v[8];
            float wj[8];
            #pragma unroll
            for (int u = 0; u < 8; u++) {
                int sj = __shfl(s, j + u);
                wj[u] = __shfl(w, j + u);
                const float* px = (sj < split) ? (xu + (size_t)sj * EMB)
                                               : (xi + (size_t)(sj - split) * EMB);
                v[u] = *(const float2*)(px + lane * 2);
            }
            #pragma unroll
            for (int u = 0; u < 8; u++) {
                ax += wj[u] * v[u].x;
                ay += wj[u] * v[u].y;
            }
        }
    }
    float wd = dinv[node];
    float2 r;
    r.x = ax * wd;
    r.y = ay * wd;
    *(float2*)(out + (size_t)node * EMB + lane * 2) = r;
}

// ---------------- fp32 GEMM + ReLU: out[M,128] = relu(A[M,128] @ W[128,128]) ----------------
// block: 256 thr, tile 64 rows x 128 cols, BK=32; thread tile 4 rows x 8 cols
// (cols c0..c0+3 and 64+c0..64+c0+3 to keep LDS reads 2-way max = free)

__global__ __launch_bounds__(256) void gemm_relu_kernel(
    const float* __restrict__ A, const float* __restrict__ W,
    float* __restrict__ out, int M) {
    __shared__ float As[64][36];   // +4 pad keeps 16B alignment, 2-way banks
    __shared__ float Ws[32][128];
    int t = threadIdx.x;
    int row0 = blockIdx.x * 64;
    int cg = t & 15, rg = t >> 4;
    int c0 = cg * 4;
    float4 acc0[4] = {};
    float4 acc1[4] = {};
    for (int k0 = 0; k0 < 128; k0 += 32) {
        // stage A tile (64x32 = 512 float4, 2 per thread)
        int f = t;
        #pragma unroll
        for (int it = 0; it < 2; it++, f += 256) {
            int r = f >> 3, kk4 = (f & 7) * 4;
            int row = row0 + r;
            float4 v = {0.f, 0.f, 0.f, 0.f};
            if (row < M) v = *(const float4*)(A + (size_t)row * EMB + k0 + kk4);
            *(float4*)&As[r][kk4] = v;
        }
        // stage W tile (32x128 = 1024 float4, 4 per thread)
        int g = t;
        #pragma unroll
        for (int it = 0; it < 4; it++, g += 256) {
            int kk = g >> 5, c4 = (g & 31) * 4;
            *(float4*)&Ws[kk][c4] = *(const float4*)(W + (size_t)(k0 + kk) * EMB + c4);
        }
        __syncthreads();
        #pragma unroll
        for (int kk4 = 0; kk4 < 32; kk4 += 4) {
            float4 a[4];
            #pragma unroll
            for (int r = 0; r < 4; r++) a[r] = *(const float4*)&As[rg * 4 + r][kk4];
            #pragma unroll
            for (int kk = 0; kk < 4; kk++) {
                float4 w0 = *(const float4*)&Ws[kk4 + kk][c0];
                float4 w1 = *(const float4*)&Ws[kk4 + kk][64 + c0];
                #pragma unroll
                for (int r = 0; r < 4; r++) {
                    float av = (kk == 0) ? a[r].x : (kk == 1) ? a[r].y
                             : (kk == 2) ? a[r].z : a[r].w;
                    acc0[r].x += av * w0.x; acc0[r].y += av * w0.y;
                    acc0[r].z += av * w0.z; acc0[r].w += av * w0.w;
                    acc1[r].x += av * w1.x; acc1[r].y += av * w1.y;
                    acc1[r].z += av * w1.z; acc1[r].w += av * w1.w;
                }
            }
        }
        __syncthreads();
    }
    #pragma unroll
    for (int r = 0; r < 4; r++) {
        int row = row0 + rg * 4 + r;
        if (row < M) {
            float4 v0 = acc0[r], v1 = acc1[r];
            v0.x = fmaxf(v0.x, 0.f); v0.y = fmaxf(v0.y, 0.f);
            v0.z = fmaxf(v0.z, 0.f); v0.w = fmaxf(v0.w, 0.f);
            v1.x = fmaxf(v1.x, 0.f); v1.y = fmaxf(v1.y, 0.f);
            v1.z = fmaxf(v1.z, 0.f); v1.w = fmaxf(v1.w, 0.f);
            *(float4*)(out + (size_t)row * EMB + c0) = v0;
            *(float4*)(out + (size_t)row * EMB + 64 + c0) = v1;
        }
    }
}

// ---------------- launch ----------------

extern "C" void kernel_launch(void* const* d_in, const int* in_sizes, int n_in,
                              void* d_out, int out_size, void* d_ws, size_t ws_size,
                              hipStream_t stream) {
    (void)n_in; (void)out_size; (void)ws_size;
    const float* Gu = (const float*)d_in[0];
    const float* Gi = (const float*)d_in[1];
    const float* W0 = (const float*)d_in[2];
    const float* W1 = (const float*)d_in[3];
    const float* W2 = (const float*)d_in[4];
    const int* ei = (const int*)d_in[5];

    int nu = in_sizes[0] / EMB;          // 60000
    int ni = in_sizes[1] / EMB;          // 40000
    int N = nu + ni;                     // 100000
    int E = in_sizes[5] / 2;             // 2000000
    const int* src = ei;
    const int* dst = ei + E;

    // workspace layout (all 16B aligned)
    float* Abuf = (float*)d_ws;                       // N*128 floats = 51.2 MB
    int* deg    = (int*)(Abuf + (size_t)N * EMB);     // N
    int* cursor = deg + N;                            // N (contiguous with deg for one memset)
    int* rowptr = cursor + N;                         // N+1
    float* dinv = (float*)(rowptr + N + 1);           // N
    int* csr    = (int*)(dinv + N);                   // E
    int* bsum   = csr + E;                            // <=128
    float* X    = (float*)d_out;                      // ping buffer + final output

    hipMemsetAsync(deg, 0, sizeof(int) * 2 * (size_t)N, stream);  // deg + cursor

    deg_kernel<<<(E + 255) / 256, 256, 0, stream>>>(dst, deg, E);
    int nb = (N + 1023) / 1024;                       // 98
    scan1_kernel<<<nb, 256, 0, stream>>>(deg, rowptr, dinv, bsum, N);
    scan2_kernel<<<1, 128, 0, stream>>>(bsum, nb);
    scan3_kernel<<<nb, 256, 0, stream>>>(rowptr, bsum, N, E);
    fill_kernel<<<(E + 255) / 256, 256, 0, stream>>>(src, dst, rowptr, cursor, csr, E);

    int aggBlocks = (N + 3) / 4;
    int gemmBlocks = (N + 63) / 64;

    // layer 1: agg over (Gu, Gi), then @W0 + relu -> X
    agg_kernel<<<aggBlocks, 256, 0, stream>>>(Gu, Gi, nu, rowptr, csr, dinv, Abuf, N);
    gemm_relu_kernel<<<gemmBlocks, 256, 0, stream>>>(Abuf, W0, X, N);
    // layer 2
    agg_kernel<<<aggBlocks, 256, 0, stream>>>(X, X + (size_t)nu * EMB, nu, rowptr, csr, dinv, Abuf, N);
    gemm_relu_kernel<<<gemmBlocks, 256, 0, stream>>>(Abuf, W1, X, N);
    // layer 3
    agg_kernel<<<aggBlocks, 256, 0, stream>>>(X, X + (size_t)nu * EMB, nu, rowptr, csr, dinv, Abuf, N);
    gemm_relu_kernel<<<gemmBlocks, 256, 0, stream>>>(Abuf, W2, X, N);
}

// Round 3
// 642.522 us; speedup vs baseline: 1.6669x; 1.2845x over previous
//
#include <hip/hip_runtime.h>
#include <hip/hip_bf16.h>

#define EMB 128

typedef unsigned int uint32;
typedef unsigned short ushort16;

__device__ __forceinline__ ushort f2bf(float f) {  // RNE, finite values
    uint32 u = __float_as_uint(f);
    return (ushort)((u + 0x7fff + ((u >> 16) & 1)) >> 16);
}

// ---------------- CSR build ----------------

__global__ void deg_kernel(const int* __restrict__ dst, int* __restrict__ deg, int E) {
    int e = blockIdx.x * blockDim.x + threadIdx.x;
    if (e < E) atomicAdd(&deg[dst[e]], 1);
}

// exclusive scan, 1024 elems/block (256 thr x 4). Also emits dinv.
__global__ void scan1_kernel(const int* __restrict__ deg, int* __restrict__ rowptr,
                             float* __restrict__ dinv, int* __restrict__ bsum, int N) {
    __shared__ int sc[256];
    int t = threadIdx.x;
    int base = blockIdx.x * 1024 + t * 4;
    int d0 = 0, d1 = 0, d2 = 0, d3 = 0;
    if (base + 3 < N) {
        int4 v = *(const int4*)(deg + base);
        d0 = v.x; d1 = v.y; d2 = v.z; d3 = v.w;
    } else {
        if (base     < N) d0 = deg[base];
        if (base + 1 < N) d1 = deg[base + 1];
        if (base + 2 < N) d2 = deg[base + 2];
        if (base + 3 < N) d3 = deg[base + 3];
    }
    int s = d0 + d1 + d2 + d3;
    sc[t] = s;
    __syncthreads();
    for (int off = 1; off < 256; off <<= 1) {
        int v = (t >= off) ? sc[t - off] : 0;
        __syncthreads();
        sc[t] += v;
        __syncthreads();
    }
    int excl = sc[t] - s;
    if (t == 255) bsum[blockIdx.x] = sc[255];
    int dd[4] = {d0, d1, d2, d3};
    int p = excl;
    #pragma unroll
    for (int j = 0; j < 4; j++) {
        int i = base + j;
        if (i < N) {
            rowptr[i] = p;
            dinv[i] = dd[j] > 0 ? rsqrtf((float)dd[j]) : 0.0f;
        }
        p += dd[j];
    }
}

__global__ void scan2_kernel(int* bsum, int nb) {  // nb <= 128
    __shared__ int sc[128];
    int t = threadIdx.x;
    int v = (t < nb) ? bsum[t] : 0;
    sc[t] = v;
    __syncthreads();
    for (int off = 1; off < 128; off <<= 1) {
        int u = (t >= off) ? sc[t - off] : 0;
        __syncthreads();
        sc[t] += u;
        __syncthreads();
    }
    if (t < nb) bsum[t] = sc[t] - v;  // exclusive
}

__global__ void scan3_kernel(int* __restrict__ rowptr, const int* __restrict__ bsum,
                             int N, int E) {
    int t = threadIdx.x, b = blockIdx.x;
    int add = bsum[b];
    int base = b * 1024 + t * 4;
    #pragma unroll
    for (int j = 0; j < 4; j++) {
        int i = base + j;
        if (i < N) rowptr[i] += add;
    }
    if (b == 0 && t == 0) rowptr[N] = E;
}

__global__ void fill_kernel(const int* __restrict__ src, const int* __restrict__ dst,
                            const int* __restrict__ rowptr, int* __restrict__ cursor,
                            int* __restrict__ csr, int E) {
    int e = blockIdx.x * blockDim.x + threadIdx.x;
    if (e < E) {
        int d = dst[e];
        int p = atomicAdd(&cursor[d], 1);
        csr[rowptr[d] + p] = src[e];
    }
}

// ---------------- aggregation + ReLU ----------------
// out[n] = relu( dinv[n] * sum_{s in N(n)} dinv[s] * Yh[s,:] )
// Yh is bf16 [N,128]: one wave per node, 1 dword (2 bf16) per lane.
// Lane-parallel index/weight prefetch, 16 independent 256B row gathers in flight.

__global__ __launch_bounds__(256) void agg_relu_kernel(
    const uint32* __restrict__ Yh,   // bf16 pairs, row stride 64 dwords
    const int* __restrict__ rowptr, const int* __restrict__ csr,
    const float* __restrict__ dinv, float* __restrict__ out, int N) {
    int node = blockIdx.x * 4 + (threadIdx.x >> 6);
    int lane = threadIdx.x & 63;
    if (node >= N) return;
    int e0 = rowptr[node], e1 = rowptr[node + 1];
    float ax = 0.0f, ay = 0.0f;
    for (int base = e0; base < e1; base += 64) {
        int n = e1 - base;
        if (n > 64) n = 64;
        int s = 0;
        float w = 0.0f;
        if (lane < n) {
            s = csr[base + lane];
            w = dinv[s];
        }
        int nn = (n + 15) & ~15;
        for (int j = 0; j < nn; j += 16) {
            uint32 p[16];
            float wj[16];
            #pragma unroll
            for (int u = 0; u < 16; u++) {
                int sj = __shfl(s, j + u);
                wj[u] = __shfl(w, j + u);
                p[u] = Yh[(size_t)sj * 64 + lane];
            }
            #pragma unroll
            for (int u = 0; u < 16; u++) {
                ax += wj[u] * __uint_as_float(p[u] << 16);
                ay += wj[u] * __uint_as_float(p[u] & 0xffff0000u);
            }
        }
    }
    float wd = dinv[node];
    float2 r;
    r.x = fmaxf(ax * wd, 0.0f);
    r.y = fmaxf(ay * wd, 0.0f);
    *(float2*)(out + (size_t)node * EMB + lane * 2) = r;
}

// ---------------- fp32 GEMM: Yh[M,128](bf16) = A[M,128] @ W[128,128] ----------------
// block: 256 thr, tile 64 rows x 128 cols, BK=32; thread tile 4 rows x 8 cols

__global__ __launch_bounds__(256) void gemm_kernel(
    const float* __restrict__ A, const float* __restrict__ W,
    ushort* __restrict__ Yh, int M) {
    __shared__ float As[64][36];
    __shared__ float Ws[32][128];
    int t = threadIdx.x;
    int row0 = blockIdx.x * 64;
    int cg = t & 15, rg = t >> 4;
    int c0 = cg * 4;
    float4 acc0[4] = {};
    float4 acc1[4] = {};
    for (int k0 = 0; k0 < 128; k0 += 32) {
        int f = t;
        #pragma unroll
        for (int it = 0; it < 2; it++, f += 256) {
            int r = f >> 3, kk4 = (f & 7) * 4;
            int row = row0 + r;
            float4 v = {0.f, 0.f, 0.f, 0.f};
            if (row < M) v = *(const float4*)(A + (size_t)row * EMB + k0 + kk4);
            *(float4*)&As[r][kk4] = v;
        }
        int g = t;
        #pragma unroll
        for (int it = 0; it < 4; it++, g += 256) {
            int kk = g >> 5, c4 = (g & 31) * 4;
            *(float4*)&Ws[kk][c4] = *(const float4*)(W + (size_t)(k0 + kk) * EMB + c4);
        }
        __syncthreads();
        #pragma unroll
        for (int kk4 = 0; kk4 < 32; kk4 += 4) {
            float4 a[4];
            #pragma unroll
            for (int r = 0; r < 4; r++) a[r] = *(const float4*)&As[rg * 4 + r][kk4];
            #pragma unroll
            for (int kk = 0; kk < 4; kk++) {
                float4 w0 = *(const float4*)&Ws[kk4 + kk][c0];
                float4 w1 = *(const float4*)&Ws[kk4 + kk][64 + c0];
                #pragma unroll
                for (int r = 0; r < 4; r++) {
                    float av = (kk == 0) ? a[r].x : (kk == 1) ? a[r].y
                             : (kk == 2) ? a[r].z : a[r].w;
                    acc0[r].x += av * w0.x; acc0[r].y += av * w0.y;
                    acc0[r].z += av * w0.z; acc0[r].w += av * w0.w;
                    acc1[r].x += av * w1.x; acc1[r].y += av * w1.y;
                    acc1[r].z += av * w1.z; acc1[r].w += av * w1.w;
                }
            }
        }
        __syncthreads();
    }
    #pragma unroll
    for (int r = 0; r < 4; r++) {
        int row = row0 + rg * 4 + r;
        if (row < M) {
            float4 v0 = acc0[r], v1 = acc1[r];
            ushort4 h0, h1;
            h0.x = f2bf(v0.x); h0.y = f2bf(v0.y); h0.z = f2bf(v0.z); h0.w = f2bf(v0.w);
            h1.x = f2bf(v1.x); h1.y = f2bf(v1.y); h1.z = f2bf(v1.z); h1.w = f2bf(v1.w);
            *(ushort4*)(Yh + (size_t)row * EMB + c0) = h0;
            *(ushort4*)(Yh + (size_t)row * EMB + 64 + c0) = h1;
        }
    }
}

// ---------------- launch ----------------

extern "C" void kernel_launch(void* const* d_in, const int* in_sizes, int n_in,
                              void* d_out, int out_size, void* d_ws, size_t ws_size,
                              hipStream_t stream) {
    (void)n_in; (void)out_size; (void)ws_size;
    const float* Gu = (const float*)d_in[0];
    const float* Gi = (const float*)d_in[1];
    const float* W0 = (const float*)d_in[2];
    const float* W1 = (const float*)d_in[3];
    const float* W2 = (const float*)d_in[4];
    const int* ei = (const int*)d_in[5];

    int nu = in_sizes[0] / EMB;          // 60000
    int ni = in_sizes[1] / EMB;          // 40000
    int N = nu + ni;                     // 100000
    int E = in_sizes[5] / 2;             // 2000000
    const int* src = ei;
    const int* dst = ei + E;

    // workspace layout (16B aligned: N*128*2 bytes = 25.6MB, /16 exact)
    ushort* Yh  = (ushort*)d_ws;                      // N*128 bf16 = 25.6 MB
    int* deg    = (int*)(Yh + (size_t)N * EMB);       // N
    int* cursor = deg + N;                            // N
    int* rowptr = cursor + N;                         // N+1
    float* dinv = (float*)(rowptr + N + 1);           // N
    int* csr    = (int*)(dinv + N);                   // E
    int* bsum   = csr + E;                            // <=128
    float* X    = (float*)d_out;                      // fp32 layer output + final

    hipMemsetAsync(deg, 0, sizeof(int) * 2 * (size_t)N, stream);  // deg + cursor

    deg_kernel<<<(E + 255) / 256, 256, 0, stream>>>(dst, deg, E);
    int nb = (N + 1023) / 1024;                       // 98
    scan1_kernel<<<nb, 256, 0, stream>>>(deg, rowptr, dinv, bsum, N);
    scan2_kernel<<<1, 128, 0, stream>>>(bsum, nb);
    scan3_kernel<<<nb, 256, 0, stream>>>(rowptr, bsum, N, E);
    fill_kernel<<<(E + 255) / 256, 256, 0, stream>>>(src, dst, rowptr, cursor, csr, E);

    int aggBlocks = (N + 3) / 4;

    // layer 1: y = concat(Gu,Gi) @ W0 (bf16 out), x = relu(agg(y))
    gemm_kernel<<<(nu + 63) / 64, 256, 0, stream>>>(Gu, W0, Yh, nu);
    gemm_kernel<<<(ni + 63) / 64, 256, 0, stream>>>(Gi, W0, Yh + (size_t)nu * EMB, ni);
    agg_relu_kernel<<<aggBlocks, 256, 0, stream>>>((const uint32*)Yh, rowptr, csr, dinv, X, N);
    // layer 2
    gemm_kernel<<<(N + 63) / 64, 256, 0, stream>>>(X, W1, Yh, N);
    agg_relu_kernel<<<aggBlocks, 256, 0, stream>>>((const uint32*)Yh, rowptr, csr, dinv, X, N);
    // layer 3
    gemm_kernel<<<(N + 63) / 64, 256, 0, stream>>>(X, W2, Yh, N);
    agg_relu_kernel<<<aggBlocks, 256, 0, stream>>>((const uint32*)Yh, rowptr, csr, dinv, X, N);
}

// Round 4
// 568.002 us; speedup vs baseline: 1.8856x; 1.1312x over previous
//
#include <hip/hip_runtime.h>
#include <hip/hip_bf16.h>

#define EMB 128
#define NPB 256          // nodes per bucket (matches >>8 and phase-B blockDim)
#define NB_PAD 512
#define CHUNK 4096       // edges per bucket_scatter block

typedef unsigned int uint32;

__device__ __forceinline__ ushort f2bf(float f) {  // RNE, finite values
    uint32 u = __float_as_uint(f);
    return (ushort)((u + 0x7fff + ((u >> 16) & 1)) >> 16);
}

// ---------------- CSR build: degree + scan ----------------

__global__ void deg_kernel(const int* __restrict__ dst, int* __restrict__ deg, int E) {
    int e = blockIdx.x * blockDim.x + threadIdx.x;
    if (e < E) atomicAdd(&deg[dst[e]], 1);
}

__global__ void scan1_kernel(const int* __restrict__ deg, int* __restrict__ rowptr,
                             float* __restrict__ dinv, int* __restrict__ bsum, int N) {
    __shared__ int sc[256];
    int t = threadIdx.x;
    int base = blockIdx.x * 1024 + t * 4;
    int d0 = 0, d1 = 0, d2 = 0, d3 = 0;
    if (base + 3 < N) {
        int4 v = *(const int4*)(deg + base);
        d0 = v.x; d1 = v.y; d2 = v.z; d3 = v.w;
    } else {
        if (base     < N) d0 = deg[base];
        if (base + 1 < N) d1 = deg[base + 1];
        if (base + 2 < N) d2 = deg[base + 2];
        if (base + 3 < N) d3 = deg[base + 3];
    }
    int s = d0 + d1 + d2 + d3;
    sc[t] = s;
    __syncthreads();
    for (int off = 1; off < 256; off <<= 1) {
        int v = (t >= off) ? sc[t - off] : 0;
        __syncthreads();
        sc[t] += v;
        __syncthreads();
    }
    int excl = sc[t] - s;
    if (t == 255) bsum[blockIdx.x] = sc[255];
    int dd[4] = {d0, d1, d2, d3};
    int p = excl;
    #pragma unroll
    for (int j = 0; j < 4; j++) {
        int i = base + j;
        if (i < N) {
            rowptr[i] = p;
            dinv[i] = dd[j] > 0 ? rsqrtf((float)dd[j]) : 0.0f;
        }
        p += dd[j];
    }
}

__global__ void scan2_kernel(int* bsum, int nb) {  // nb <= 128
    __shared__ int sc[128];
    int t = threadIdx.x;
    int v = (t < nb) ? bsum[t] : 0;
    sc[t] = v;
    __syncthreads();
    for (int off = 1; off < 128; off <<= 1) {
        int u = (t >= off) ? sc[t - off] : 0;
        __syncthreads();
        sc[t] += u;
        __syncthreads();
    }
    if (t < nb) bsum[t] = sc[t] - v;  // exclusive
}

__global__ void scan3_kernel(int* __restrict__ rowptr, const int* __restrict__ bsum,
                             int N, int E) {
    int t = threadIdx.x, b = blockIdx.x;
    int add = bsum[b];
    int base = b * 1024 + t * 4;
    #pragma unroll
    for (int j = 0; j < 4; j++) {
        int i = base + j;
        if (i < N) rowptr[i] += add;
    }
    if (b == 0 && t == 0) rowptr[N] = E;
}

__global__ void cursor_init_kernel(const int* __restrict__ rowptr,
                                   int* __restrict__ gcursor, int NB) {
    int i = blockIdx.x * blockDim.x + threadIdx.x;
    if (i < NB) gcursor[i] = rowptr[i * NPB];
}

// ---------------- Phase A: scatter edges into bucket-grouped (src,dst) pairs ----------------

__global__ __launch_bounds__(256) void bucket_scatter_kernel(
    const int* __restrict__ src, const int* __restrict__ dst,
    int* __restrict__ gcursor, uint2* __restrict__ ebuf, int E, int NB) {
    __shared__ int cnt[NB_PAD];
    __shared__ int loff[NB_PAD];
    __shared__ int gbase[NB_PAD];
    __shared__ int pos[NB_PAD];
    __shared__ int sc[256];
    __shared__ uint2 stage[CHUNK];
    int t = threadIdx.x;
    long e0 = (long)blockIdx.x * CHUNK;
    int n = E - (int)e0; if (n > CHUNK) n = CHUNK;
    for (int b = t; b < NB_PAD; b += 256) { cnt[b] = 0; pos[b] = 0; }
    __syncthreads();
    int es[CHUNK / 256], ed[CHUNK / 256];
    #pragma unroll
    for (int i = 0; i < CHUNK / 256; i++) {
        int idx = t + i * 256;
        if (idx < n) {
            es[i] = src[e0 + idx];
            ed[i] = dst[e0 + idx];
            atomicAdd(&cnt[ed[i] >> 8], 1);
        }
    }
    __syncthreads();
    // exclusive scan of cnt[0..511] -> loff
    int a = cnt[2 * t], b2 = cnt[2 * t + 1];
    sc[t] = a + b2;
    __syncthreads();
    for (int off = 1; off < 256; off <<= 1) {
        int v = (t >= off) ? sc[t - off] : 0;
        __syncthreads();
        sc[t] += v;
        __syncthreads();
    }
    int excl = sc[t] - (a + b2);
    loff[2 * t] = excl;
    loff[2 * t + 1] = excl + a;
    __syncthreads();
    // reserve global ranges (one atomic per non-empty bucket per block)
    for (int b = t; b < NB; b += 256)
        if (cnt[b] > 0) gbase[b] = atomicAdd(&gcursor[b], cnt[b]);
    __syncthreads();
    // group edges by bucket in LDS staging
    #pragma unroll
    for (int i = 0; i < CHUNK / 256; i++) {
        int idx = t + i * 256;
        if (idx < n) {
            int b = ed[i] >> 8;
            int p = atomicAdd(&pos[b], 1);
            stage[loff[b] + p] = make_uint2((uint32)es[i], (uint32)ed[i]);
        }
    }
    __syncthreads();
    // write contiguous runs per bucket
    for (int b = t; b < NB; b += 256) {
        int c = cnt[b], lo = loff[b], go = gbase[b];
        for (int k = 0; k < c; k++) ebuf[go + k] = stage[lo + k];
    }
}

// ---------------- Phase B: per-bucket fill of csr (writes confined to one L2) ----------------

__global__ __launch_bounds__(256) void bucket_fill_kernel(
    const uint2* __restrict__ ebuf, const int* __restrict__ rowptr,
    int* __restrict__ csr, int N) {
    __shared__ int cnt[NPB];
    __shared__ int rp[NPB];
    int t = threadIdx.x;
    int n0 = blockIdx.x * NPB;
    int nn = N - n0; if (nn > NPB) nn = NPB;
    if (t < nn) { cnt[t] = 0; rp[t] = rowptr[n0 + t]; }
    __syncthreads();
    int e0 = rowptr[n0];
    int e1 = rowptr[n0 + nn];
    for (int e = e0 + t; e < e1; e += 256) {
        uint2 sd = ebuf[e];
        int local = (int)sd.y - n0;
        int p = atomicAdd(&cnt[local], 1);
        csr[rp[local] + p] = (int)sd.x;
    }
}

// ---------------- aggregation + ReLU ----------------
// out[n] = relu( dinv[n] * sum_{s in N(n)} dinv[s] * Yh[s,:] ), Yh bf16 [N,128]

__global__ __launch_bounds__(256) void agg_relu_kernel(
    const uint32* __restrict__ Yh,   // bf16 pairs, row stride 64 dwords
    const int* __restrict__ rowptr, const int* __restrict__ csr,
    const float* __restrict__ dinv, float* __restrict__ out, int N) {
    int node = blockIdx.x * 4 + (threadIdx.x >> 6);
    int lane = threadIdx.x & 63;
    if (node >= N) return;
    int e0 = rowptr[node], e1 = rowptr[node + 1];
    float ax = 0.0f, ay = 0.0f;
    for (int base = e0; base < e1; base += 64) {
        int n = e1 - base;
        if (n > 64) n = 64;
        int s = 0;
        float w = 0.0f;
        if (lane < n) {
            s = csr[base + lane];
            w = dinv[s];
        }
        int nn = (n + 15) & ~15;
        for (int j = 0; j < nn; j += 16) {
            uint32 p[16];
            float wj[16];
            #pragma unroll
            for (int u = 0; u < 16; u++) {
                int sj = __shfl(s, j + u);
                wj[u] = __shfl(w, j + u);
                p[u] = Yh[(size_t)sj * 64 + lane];
            }
            #pragma unroll
            for (int u = 0; u < 16; u++) {
                ax += wj[u] * __uint_as_float(p[u] << 16);
                ay += wj[u] * __uint_as_float(p[u] & 0xffff0000u);
            }
        }
    }
    float wd = dinv[node];
    float2 r;
    r.x = fmaxf(ax * wd, 0.0f);
    r.y = fmaxf(ay * wd, 0.0f);
    *(float2*)(out + (size_t)node * EMB + lane * 2) = r;
}

// ---------------- fp32 GEMM: Yh[M,128](bf16) = A[M,128] @ W[128,128] ----------------

__global__ __launch_bounds__(256) void gemm_kernel(
    const float* __restrict__ A, const float* __restrict__ W,
    ushort* __restrict__ Yh, int M) {
    __shared__ float As[64][36];
    __shared__ float Ws[32][128];
    int t = threadIdx.x;
    int row0 = blockIdx.x * 64;
    int cg = t & 15, rg = t >> 4;
    int c0 = cg * 4;
    float4 acc0[4] = {};
    float4 acc1[4] = {};
    for (int k0 = 0; k0 < 128; k0 += 32) {
        int f = t;
        #pragma unroll
        for (int it = 0; it < 2; it++, f += 256) {
            int r = f >> 3, kk4 = (f & 7) * 4;
            int row = row0 + r;
            float4 v = {0.f, 0.f, 0.f, 0.f};
            if (row < M) v = *(const float4*)(A + (size_t)row * EMB + k0 + kk4);
            *(float4*)&As[r][kk4] = v;
        }
        int g = t;
        #pragma unroll
        for (int it = 0; it < 4; it++, g += 256) {
            int kk = g >> 5, c4 = (g & 31) * 4;
            *(float4*)&Ws[kk][c4] = *(const float4*)(W + (size_t)(k0 + kk) * EMB + c4);
        }
        __syncthreads();
        #pragma unroll
        for (int kk4 = 0; kk4 < 32; kk4 += 4) {
            float4 a[4];
            #pragma unroll
            for (int r = 0; r < 4; r++) a[r] = *(const float4*)&As[rg * 4 + r][kk4];
            #pragma unroll
            for (int kk = 0; kk < 4; kk++) {
                float4 w0 = *(const float4*)&Ws[kk4 + kk][c0];
                float4 w1 = *(const float4*)&Ws[kk4 + kk][64 + c0];
                #pragma unroll
                for (int r = 0; r < 4; r++) {
                    float av = (kk == 0) ? a[r].x : (kk == 1) ? a[r].y
                             : (kk == 2) ? a[r].z : a[r].w;
                    acc0[r].x += av * w0.x; acc0[r].y += av * w0.y;
                    acc0[r].z += av * w0.z; acc0[r].w += av * w0.w;
                    acc1[r].x += av * w1.x; acc1[r].y += av * w1.y;
                    acc1[r].z += av * w1.z; acc1[r].w += av * w1.w;
                }
            }
        }
        __syncthreads();
    }
    #pragma unroll
    for (int r = 0; r < 4; r++) {
        int row = row0 + rg * 4 + r;
        if (row < M) {
            float4 v0 = acc0[r], v1 = acc1[r];
            ushort4 h0, h1;
            h0.x = f2bf(v0.x); h0.y = f2bf(v0.y); h0.z = f2bf(v0.z); h0.w = f2bf(v0.w);
            h1.x = f2bf(v1.x); h1.y = f2bf(v1.y); h1.z = f2bf(v1.z); h1.w = f2bf(v1.w);
            *(ushort4*)(Yh + (size_t)row * EMB + c0) = h0;
            *(ushort4*)(Yh + (size_t)row * EMB + 64 + c0) = h1;
        }
    }
}

// ---------------- launch ----------------

extern "C" void kernel_launch(void* const* d_in, const int* in_sizes, int n_in,
                              void* d_out, int out_size, void* d_ws, size_t ws_size,
                              hipStream_t stream) {
    (void)n_in; (void)out_size; (void)ws_size;
    const float* Gu = (const float*)d_in[0];
    const float* Gi = (const float*)d_in[1];
    const float* W0 = (const float*)d_in[2];
    const float* W1 = (const float*)d_in[3];
    const float* W2 = (const float*)d_in[4];
    const int* ei = (const int*)d_in[5];

    int nu = in_sizes[0] / EMB;          // 60000
    int ni = in_sizes[1] / EMB;          // 40000
    int N = nu + ni;                     // 100000
    int E = in_sizes[5] / 2;             // 2000000
    const int* src = ei;
    const int* dst = ei + E;
    int NB = (N + NPB - 1) / NPB;        // 391

    // workspace layout
    ushort* Yh   = (ushort*)d_ws;                     // N*128 bf16 = 25.6 MB
    uint2* ebuf  = (uint2*)(Yh + (size_t)N * EMB);    // E pairs = 16 MB
    int* deg     = (int*)(ebuf + (size_t)E);          // N
    int* rowptr  = deg + N;                           // N+1
    float* dinv  = (float*)(rowptr + N + 1);          // N
    int* csr     = (int*)(dinv + N);                  // E
    int* gcursor = csr + E;                           // NB
    int* bsum    = gcursor + NB;                      // <=128
    float* X     = (float*)d_out;                     // fp32 layer output + final

    hipMemsetAsync(deg, 0, sizeof(int) * (size_t)N, stream);

    deg_kernel<<<(E + 255) / 256, 256, 0, stream>>>(dst, deg, E);
    int nb = (N + 1023) / 1024;                       // 98
    scan1_kernel<<<nb, 256, 0, stream>>>(deg, rowptr, dinv, bsum, N);
    scan2_kernel<<<1, 128, 0, stream>>>(bsum, nb);
    scan3_kernel<<<nb, 256, 0, stream>>>(rowptr, bsum, N, E);
    cursor_init_kernel<<<(NB + 255) / 256, 256, 0, stream>>>(rowptr, gcursor, NB);
    bucket_scatter_kernel<<<(E + CHUNK - 1) / CHUNK, 256, 0, stream>>>(src, dst, gcursor, ebuf, E, NB);
    bucket_fill_kernel<<<NB, 256, 0, stream>>>(ebuf, rowptr, csr, N);

    int aggBlocks = (N + 3) / 4;

    // layer 1: y = concat(Gu,Gi) @ W0 (bf16 out), x = relu(agg(y))
    gemm_kernel<<<(nu + 63) / 64, 256, 0, stream>>>(Gu, W0, Yh, nu);
    gemm_kernel<<<(ni + 63) / 64, 256, 0, stream>>>(Gi, W0, Yh + (size_t)nu * EMB, ni);
    agg_relu_kernel<<<aggBlocks, 256, 0, stream>>>((const uint32*)Yh, rowptr, csr, dinv, X, N);
    // layer 2
    gemm_kernel<<<(N + 63) / 64, 256, 0, stream>>>(X, W1, Yh, N);
    agg_relu_kernel<<<aggBlocks, 256, 0, stream>>>((const uint32*)Yh, rowptr, csr, dinv, X, N);
    // layer 3
    gemm_kernel<<<(N + 63) / 64, 256, 0, stream>>>(X, W2, Yh, N);
    agg_relu_kernel<<<aggBlocks, 256, 0, stream>>>((const uint32*)Yh, rowptr, csr, dinv, X, N);
}

// Round 5
// 498.208 us; speedup vs baseline: 2.1497x; 1.1401x over previous
//
#include <hip/hip_runtime.h>
#include <hip/hip_bf16.h>

#define EMB 128
#define NPB 256          // nodes per bucket (matches >>8 and phase-B blockDim)
#define NB_PAD 512
#define CHUNK 4096       // edges per bucket_scatter/count block

typedef unsigned int uint32;

__device__ __forceinline__ ushort f2bf(float f) {  // RNE, finite values
    uint32 u = __float_as_uint(f);
    return (ushort)((u + 0x7fff + ((u >> 16) & 1)) >> 16);
}

// ---------------- bucket histogram of dst>>8 ----------------

__global__ __launch_bounds__(256) void bucket_count_kernel(
    const int* __restrict__ dst, int* __restrict__ bucket_cnt, int E, int NB) {
    __shared__ int cnt[NB_PAD];
    int t = threadIdx.x;
    long e0 = (long)blockIdx.x * CHUNK;
    int n = E - (int)e0; if (n > CHUNK) n = CHUNK;
    for (int b = t; b < NB_PAD; b += 256) cnt[b] = 0;
    __syncthreads();
    #pragma unroll
    for (int i = 0; i < CHUNK / 256; i++) {
        int idx = t + i * 256;
        if (idx < n) atomicAdd(&cnt[dst[e0 + idx] >> 8], 1);
    }
    __syncthreads();
    for (int b = t; b < NB; b += 256)
        if (cnt[b] > 0) atomicAdd(&bucket_cnt[b], cnt[b]);
}

// exclusive scan of bucket_cnt[NB] (NB<=512) -> ebase[NB+1], gcursor[NB]
__global__ void bucket_scan_kernel(const int* __restrict__ bucket_cnt,
                                   int* __restrict__ ebase, int* __restrict__ gcursor,
                                   int NB, int E) {
    __shared__ int sc[512];
    int t = threadIdx.x;
    int v = (t < NB) ? bucket_cnt[t] : 0;
    sc[t] = v;
    __syncthreads();
    for (int off = 1; off < 512; off <<= 1) {
        int u = (t >= off) ? sc[t - off] : 0;
        __syncthreads();
        sc[t] += u;
        __syncthreads();
    }
    if (t < NB) {
        int excl = sc[t] - v;
        ebase[t] = excl;
        gcursor[t] = excl;
    }
    if (t == 0) ebase[NB] = E;
}

// ---------------- Phase A: scatter edges into bucket-grouped (src,dst) pairs ----------------

__global__ __launch_bounds__(256) void bucket_scatter_kernel(
    const int* __restrict__ src, const int* __restrict__ dst,
    int* __restrict__ gcursor, uint2* __restrict__ ebuf, int E, int NB) {
    __shared__ int cnt[NB_PAD];
    __shared__ int loff[NB_PAD];
    __shared__ int gbase[NB_PAD];
    __shared__ int pos[NB_PAD];
    __shared__ int sc[256];
    __shared__ uint2 stage[CHUNK];
    int t = threadIdx.x;
    long e0 = (long)blockIdx.x * CHUNK;
    int n = E - (int)e0; if (n > CHUNK) n = CHUNK;
    for (int b = t; b < NB_PAD; b += 256) { cnt[b] = 0; pos[b] = 0; }
    __syncthreads();
    int es[CHUNK / 256], ed[CHUNK / 256];
    #pragma unroll
    for (int i = 0; i < CHUNK / 256; i++) {
        int idx = t + i * 256;
        if (idx < n) {
            es[i] = src[e0 + idx];
            ed[i] = dst[e0 + idx];
            atomicAdd(&cnt[ed[i] >> 8], 1);
        }
    }
    __syncthreads();
    // exclusive scan of cnt[0..511] -> loff
    int a = cnt[2 * t], b2 = cnt[2 * t + 1];
    sc[t] = a + b2;
    __syncthreads();
    for (int off = 1; off < 256; off <<= 1) {
        int v = (t >= off) ? sc[t - off] : 0;
        __syncthreads();
        sc[t] += v;
        __syncthreads();
    }
    int excl = sc[t] - (a + b2);
    loff[2 * t] = excl;
    loff[2 * t + 1] = excl + a;
    __syncthreads();
    // reserve global ranges (one atomic per non-empty bucket per block)
    for (int b = t; b < NB; b += 256)
        if (cnt[b] > 0) gbase[b] = atomicAdd(&gcursor[b], cnt[b]);
    __syncthreads();
    // group edges by bucket in LDS staging
    #pragma unroll
    for (int i = 0; i < CHUNK / 256; i++) {
        int idx = t + i * 256;
        if (idx < n) {
            int b = ed[i] >> 8;
            int p = atomicAdd(&pos[b], 1);
            stage[loff[b] + p] = make_uint2((uint32)es[i], (uint32)ed[i]);
        }
    }
    __syncthreads();
    // write contiguous runs per bucket
    for (int b = t; b < NB; b += 256) {
        int c = cnt[b], lo = loff[b], go = gbase[b];
        for (int k = 0; k < c; k++) ebuf[go + k] = stage[lo + k];
    }
}

// ---------------- per-bucket degree + dinv (coalesced writes, LDS atomics) ----------------

__global__ __launch_bounds__(256) void bucket_deg_kernel(
    const uint2* __restrict__ ebuf, const int* __restrict__ ebase,
    int* __restrict__ deg, float* __restrict__ dinv, int N) {
    __shared__ int cnt[NPB];
    int t = threadIdx.x;
    int n0 = blockIdx.x * NPB;
    int nn = N - n0; if (nn > NPB) nn = NPB;
    cnt[t] = 0;
    __syncthreads();
    int e0 = ebase[blockIdx.x];
    int e1 = ebase[blockIdx.x + 1];
    for (int e = e0 + t; e < e1; e += 256) {
        uint2 sd = ebuf[e];
        atomicAdd(&cnt[(int)sd.y - n0], 1);
    }
    __syncthreads();
    if (t < nn) {
        int c = cnt[t];
        deg[n0 + t] = c;
        dinv[n0 + t] = c > 0 ? rsqrtf((float)c) : 0.0f;
    }
}

// ---------------- rowptr scan ----------------

__global__ void scan1_kernel(const int* __restrict__ deg, int* __restrict__ rowptr,
                             int* __restrict__ bsum, int N) {
    __shared__ int sc[256];
    int t = threadIdx.x;
    int base = blockIdx.x * 1024 + t * 4;
    int d0 = 0, d1 = 0, d2 = 0, d3 = 0;
    if (base + 3 < N) {
        int4 v = *(const int4*)(deg + base);
        d0 = v.x; d1 = v.y; d2 = v.z; d3 = v.w;
    } else {
        if (base     < N) d0 = deg[base];
        if (base + 1 < N) d1 = deg[base + 1];
        if (base + 2 < N) d2 = deg[base + 2];
        if (base + 3 < N) d3 = deg[base + 3];
    }
    int s = d0 + d1 + d2 + d3;
    sc[t] = s;
    __syncthreads();
    for (int off = 1; off < 256; off <<= 1) {
        int v = (t >= off) ? sc[t - off] : 0;
        __syncthreads();
        sc[t] += v;
        __syncthreads();
    }
    int excl = sc[t] - s;
    if (t == 255) bsum[blockIdx.x] = sc[255];
    int dd[4] = {d0, d1, d2, d3};
    int p = excl;
    #pragma unroll
    for (int j = 0; j < 4; j++) {
        int i = base + j;
        if (i < N) rowptr[i] = p;
        p += dd[j];
    }
}

__global__ void scan2_kernel(int* bsum, int nb) {  // nb <= 128
    __shared__ int sc[128];
    int t = threadIdx.x;
    int v = (t < nb) ? bsum[t] : 0;
    sc[t] = v;
    __syncthreads();
    for (int off = 1; off < 128; off <<= 1) {
        int u = (t >= off) ? sc[t - off] : 0;
        __syncthreads();
        sc[t] += u;
        __syncthreads();
    }
    if (t < nb) bsum[t] = sc[t] - v;  // exclusive
}

__global__ void scan3_kernel(int* __restrict__ rowptr, const int* __restrict__ bsum,
                             int N, int E) {
    int t = threadIdx.x, b = blockIdx.x;
    int add = bsum[b];
    int base = b * 1024 + t * 4;
    #pragma unroll
    for (int j = 0; j < 4; j++) {
        int i = base + j;
        if (i < N) rowptr[i] += add;
    }
    if (b == 0 && t == 0) rowptr[N] = E;
}

// ---------------- Phase B: per-bucket fill of csr (writes confined to one L2) ----------------

__global__ __launch_bounds__(256) void bucket_fill_kernel(
    const uint2* __restrict__ ebuf, const int* __restrict__ rowptr,
    int* __restrict__ csr, int N) {
    __shared__ int cnt[NPB];
    __shared__ int rp[NPB];
    int t = threadIdx.x;
    int n0 = blockIdx.x * NPB;
    int nn = N - n0; if (nn > NPB) nn = NPB;
    if (t < nn) { cnt[t] = 0; rp[t] = rowptr[n0 + t]; }
    __syncthreads();
    int e0 = rowptr[n0];
    int e1 = rowptr[n0 + nn];
    for (int e = e0 + t; e < e1; e += 256) {
        uint2 sd = ebuf[e];
        int local = (int)sd.y - n0;
        int p = atomicAdd(&cnt[local], 1);
        csr[rp[local] + p] = (int)sd.x;
    }
}

// ---------------- aggregation + ReLU ----------------
// out[n] = relu( dinv[n] * sum_{s in N(n)} dinv[s] * Yh[s,:] ), Yh bf16 [N,128]

__global__ __launch_bounds__(256) void agg_relu_kernel(
    const uint32* __restrict__ Yh,   // bf16 pairs, row stride 64 dwords
    const int* __restrict__ rowptr, const int* __restrict__ csr,
    const float* __restrict__ dinv, float* __restrict__ out, int N) {
    int node = blockIdx.x * 4 + (threadIdx.x >> 6);
    int lane = threadIdx.x & 63;
    if (node >= N) return;
    int e0 = rowptr[node], e1 = rowptr[node + 1];
    float ax = 0.0f, ay = 0.0f;
    for (int base = e0; base < e1; base += 64) {
        int n = e1 - base;
        if (n > 64) n = 64;
        int s = 0;
        float w = 0.0f;
        if (lane < n) {
            s = csr[base + lane];
            w = dinv[s];
        }
        int nn = (n + 15) & ~15;
        for (int j = 0; j < nn; j += 16) {
            uint32 p[16];
            float wj[16];
            #pragma unroll
            for (int u = 0; u < 16; u++) {
                int sj = __shfl(s, j + u);
                wj[u] = __shfl(w, j + u);
                p[u] = Yh[(size_t)sj * 64 + lane];
            }
            #pragma unroll
            for (int u = 0; u < 16; u++) {
                ax += wj[u] * __uint_as_float(p[u] << 16);
                ay += wj[u] * __uint_as_float(p[u] & 0xffff0000u);
            }
        }
    }
    float wd = dinv[node];
    float2 r;
    r.x = fmaxf(ax * wd, 0.0f);
    r.y = fmaxf(ay * wd, 0.0f);
    *(float2*)(out + (size_t)node * EMB + lane * 2) = r;
}

// ---------------- fp32 GEMM: Yh[M,128](bf16) = A[M,128] @ W[128,128] ----------------

__global__ __launch_bounds__(256) void gemm_kernel(
    const float* __restrict__ A, const float* __restrict__ W,
    ushort* __restrict__ Yh, int M) {
    __shared__ float As[64][36];
    __shared__ float Ws[32][128];
    int t = threadIdx.x;
    int row0 = blockIdx.x * 64;
    int cg = t & 15, rg = t >> 4;
    int c0 = cg * 4;
    float4 acc0[4] = {};
    float4 acc1[4] = {};
    for (int k0 = 0; k0 < 128; k0 += 32) {
        int f = t;
        #pragma unroll
        for (int it = 0; it < 2; it++, f += 256) {
            int r = f >> 3, kk4 = (f & 7) * 4;
            int row = row0 + r;
            float4 v = {0.f, 0.f, 0.f, 0.f};
            if (row < M) v = *(const float4*)(A + (size_t)row * EMB + k0 + kk4);
            *(float4*)&As[r][kk4] = v;
        }
        int g = t;
        #pragma unroll
        for (int it = 0; it < 4; it++, g += 256) {
            int kk = g >> 5, c4 = (g & 31) * 4;
            *(float4*)&Ws[kk][c4] = *(const float4*)(W + (size_t)(k0 + kk) * EMB + c4);
        }
        __syncthreads();
        #pragma unroll
        for (int kk4 = 0; kk4 < 32; kk4 += 4) {
            float4 a[4];
            #pragma unroll
            for (int r = 0; r < 4; r++) a[r] = *(const float4*)&As[rg * 4 + r][kk4];
            #pragma unroll
            for (int kk = 0; kk < 4; kk++) {
                float4 w0 = *(const float4*)&Ws[kk4 + kk][c0];
                float4 w1 = *(const float4*)&Ws[kk4 + kk][64 + c0];
                #pragma unroll
                for (int r = 0; r < 4; r++) {
                    float av = (kk == 0) ? a[r].x : (kk == 1) ? a[r].y
                             : (kk == 2) ? a[r].z : a[r].w;
                    acc0[r].x += av * w0.x; acc0[r].y += av * w0.y;
                    acc0[r].z += av * w0.z; acc0[r].w += av * w0.w;
                    acc1[r].x += av * w1.x; acc1[r].y += av * w1.y;
                    acc1[r].z += av * w1.z; acc1[r].w += av * w1.w;
                }
            }
        }
        __syncthreads();
    }
    #pragma unroll
    for (int r = 0; r < 4; r++) {
        int row = row0 + rg * 4 + r;
        if (row < M) {
            float4 v0 = acc0[r], v1 = acc1[r];
            ushort4 h0, h1;
            h0.x = f2bf(v0.x); h0.y = f2bf(v0.y); h0.z = f2bf(v0.z); h0.w = f2bf(v0.w);
            h1.x = f2bf(v1.x); h1.y = f2bf(v1.y); h1.z = f2bf(v1.z); h1.w = f2bf(v1.w);
            *(ushort4*)(Yh + (size_t)row * EMB + c0) = h0;
            *(ushort4*)(Yh + (size_t)row * EMB + 64 + c0) = h1;
        }
    }
}

// ---------------- launch ----------------

extern "C" void kernel_launch(void* const* d_in, const int* in_sizes, int n_in,
                              void* d_out, int out_size, void* d_ws, size_t ws_size,
                              hipStream_t stream) {
    (void)n_in; (void)out_size; (void)ws_size;
    const float* Gu = (const float*)d_in[0];
    const float* Gi = (const float*)d_in[1];
    const float* W0 = (const float*)d_in[2];
    const float* W1 = (const float*)d_in[3];
    const float* W2 = (const float*)d_in[4];
    const int* ei = (const int*)d_in[5];

    int nu = in_sizes[0] / EMB;          // 60000
    int ni = in_sizes[1] / EMB;          // 40000
    int N = nu + ni;                     // 100000
    int E = in_sizes[5] / 2;             // 2000000
    const int* src = ei;
    const int* dst = ei + E;
    int NB = (N + NPB - 1) / NPB;        // 391

    // workspace layout
    ushort* Yh      = (ushort*)d_ws;                   // N*128 bf16 = 25.6 MB
    uint2* ebuf     = (uint2*)(Yh + (size_t)N * EMB);  // E pairs = 16 MB
    int* deg        = (int*)(ebuf + (size_t)E);        // N
    int* rowptr     = deg + N;                         // N+1
    float* dinv     = (float*)(rowptr + N + 1);        // N
    int* csr        = (int*)(dinv + N);                // E
    int* bucket_cnt = csr + E;                         // NB
    int* ebase      = bucket_cnt + NB;                 // NB+1
    int* gcursor    = ebase + NB + 1;                  // NB
    int* bsum       = gcursor + NB;                    // <=128
    float* X        = (float*)d_out;                   // fp32 layer output + final

    hipMemsetAsync(bucket_cnt, 0, sizeof(int) * (size_t)NB, stream);

    int ecb = (E + CHUNK - 1) / CHUNK;                 // 489
    bucket_count_kernel<<<ecb, 256, 0, stream>>>(dst, bucket_cnt, E, NB);
    bucket_scan_kernel<<<1, 512, 0, stream>>>(bucket_cnt, ebase, gcursor, NB, E);
    bucket_scatter_kernel<<<ecb, 256, 0, stream>>>(src, dst, gcursor, ebuf, E, NB);
    bucket_deg_kernel<<<NB, 256, 0, stream>>>(ebuf, ebase, deg, dinv, N);
    int nb = (N + 1023) / 1024;                        // 98
    scan1_kernel<<<nb, 256, 0, stream>>>(deg, rowptr, bsum, N);
    scan2_kernel<<<1, 128, 0, stream>>>(bsum, nb);
    scan3_kernel<<<nb, 256, 0, stream>>>(rowptr, bsum, N, E);
    bucket_fill_kernel<<<NB, 256, 0, stream>>>(ebuf, rowptr, csr, N);

    int aggBlocks = (N + 3) / 4;

    // layer 1: y = concat(Gu,Gi) @ W0 (bf16 out), x = relu(agg(y))
    gemm_kernel<<<(nu + 63) / 64, 256, 0, stream>>>(Gu, W0, Yh, nu);
    gemm_kernel<<<(ni + 63) / 64, 256, 0, stream>>>(Gi, W0, Yh + (size_t)nu * EMB, ni);
    agg_relu_kernel<<<aggBlocks, 256, 0, stream>>>((const uint32*)Yh, rowptr, csr, dinv, X, N);
    // layer 2
    gemm_kernel<<<(N + 63) / 64, 256, 0, stream>>>(X, W1, Yh, N);
    agg_relu_kernel<<<aggBlocks, 256, 0, stream>>>((const uint32*)Yh, rowptr, csr, dinv, X, N);
    // layer 3
    gemm_kernel<<<(N + 63) / 64, 256, 0, stream>>>(X, W2, Yh, N);
    agg_relu_kernel<<<aggBlocks, 256, 0, stream>>>((const uint32*)Yh, rowptr, csr, dinv, X, N);
}

// Round 6
// 470.515 us; speedup vs baseline: 2.2763x; 1.0589x over previous
//
#include <hip/hip_runtime.h>
#include <hip/hip_bf16.h>

#define EMB 128
#define NPB 256          // nodes per bucket (matches >>8 and phase-B blockDim)
#define NB_PAD 512
#define CHUNK 4096       // edges per bucket_scatter/count block

typedef unsigned int uint32;
typedef __attribute__((ext_vector_type(8))) short bf16x8;
typedef __attribute__((ext_vector_type(4))) float f32x4;

__device__ __forceinline__ ushort f2bf(float f) {  // RNE, finite values
    uint32 u = __float_as_uint(f);
    return (ushort)((u + 0x7fff + ((u >> 16) & 1)) >> 16);
}
// pack bf16(RTZ) of x0 (low) and x1 (high) into one dword
__device__ __forceinline__ uint32 pack_hi2(uint32 u0, uint32 u1) {
    return (u1 & 0xffff0000u) | (u0 >> 16);
}

// ---------------- bucket histogram of dst>>8 ----------------

__global__ __launch_bounds__(256) void bucket_count_kernel(
    const int* __restrict__ dst, int* __restrict__ bucket_cnt, int E, int NB) {
    __shared__ int cnt[NB_PAD];
    int t = threadIdx.x;
    long e0 = (long)blockIdx.x * CHUNK;
    int n = E - (int)e0; if (n > CHUNK) n = CHUNK;
    for (int b = t; b < NB_PAD; b += 256) cnt[b] = 0;
    __syncthreads();
    #pragma unroll
    for (int i = 0; i < CHUNK / 256; i++) {
        int idx = t + i * 256;
        if (idx < n) atomicAdd(&cnt[dst[e0 + idx] >> 8], 1);
    }
    __syncthreads();
    for (int b = t; b < NB; b += 256)
        if (cnt[b] > 0) atomicAdd(&bucket_cnt[b], cnt[b]);
}

// exclusive scan of bucket_cnt[NB] (NB<=512) -> ebase[NB+1], gcursor[NB]
__global__ void bucket_scan_kernel(const int* __restrict__ bucket_cnt,
                                   int* __restrict__ ebase, int* __restrict__ gcursor,
                                   int NB, int E) {
    __shared__ int sc[512];
    int t = threadIdx.x;
    int v = (t < NB) ? bucket_cnt[t] : 0;
    sc[t] = v;
    __syncthreads();
    for (int off = 1; off < 512; off <<= 1) {
        int u = (t >= off) ? sc[t - off] : 0;
        __syncthreads();
        sc[t] += u;
        __syncthreads();
    }
    if (t < NB) {
        int excl = sc[t] - v;
        ebase[t] = excl;
        gcursor[t] = excl;
    }
    if (t == 0) ebase[NB] = E;
}

// ---------------- Phase A: scatter edges into bucket-grouped (src,dst) pairs ----------------

__global__ __launch_bounds__(256) void bucket_scatter_kernel(
    const int* __restrict__ src, const int* __restrict__ dst,
    int* __restrict__ gcursor, uint2* __restrict__ ebuf, int E, int NB) {
    __shared__ int cnt[NB_PAD];
    __shared__ int loff[NB_PAD];
    __shared__ int gbase[NB_PAD];
    __shared__ int pos[NB_PAD];
    __shared__ int sc[256];
    __shared__ uint2 stage[CHUNK];
    int t = threadIdx.x;
    long e0 = (long)blockIdx.x * CHUNK;
    int n = E - (int)e0; if (n > CHUNK) n = CHUNK;
    for (int b = t; b < NB_PAD; b += 256) { cnt[b] = 0; pos[b] = 0; }
    __syncthreads();
    int es[CHUNK / 256], ed[CHUNK / 256];
    #pragma unroll
    for (int i = 0; i < CHUNK / 256; i++) {
        int idx = t + i * 256;
        if (idx < n) {
            es[i] = src[e0 + idx];
            ed[i] = dst[e0 + idx];
            atomicAdd(&cnt[ed[i] >> 8], 1);
        }
    }
    __syncthreads();
    // exclusive scan of cnt[0..511] -> loff
    int a = cnt[2 * t], b2 = cnt[2 * t + 1];
    sc[t] = a + b2;
    __syncthreads();
    for (int off = 1; off < 256; off <<= 1) {
        int v = (t >= off) ? sc[t - off] : 0;
        __syncthreads();
        sc[t] += v;
        __syncthreads();
    }
    int excl = sc[t] - (a + b2);
    loff[2 * t] = excl;
    loff[2 * t + 1] = excl + a;
    __syncthreads();
    // reserve global ranges (one atomic per non-empty bucket per block)
    for (int b = t; b < NB; b += 256)
        if (cnt[b] > 0) gbase[b] = atomicAdd(&gcursor[b], cnt[b]);
    __syncthreads();
    // group edges by bucket in LDS staging
    #pragma unroll
    for (int i = 0; i < CHUNK / 256; i++) {
        int idx = t + i * 256;
        if (idx < n) {
            int b = ed[i] >> 8;
            int p = atomicAdd(&pos[b], 1);
            stage[loff[b] + p] = make_uint2((uint32)es[i], (uint32)ed[i]);
        }
    }
    __syncthreads();
    // write contiguous runs per bucket
    for (int b = t; b < NB; b += 256) {
        int c = cnt[b], lo = loff[b], go = gbase[b];
        for (int k = 0; k < c; k++) ebuf[go + k] = stage[lo + k];
    }
}

// ---------------- per-bucket degree + dinv (coalesced writes, LDS atomics) ----------------

__global__ __launch_bounds__(256) void bucket_deg_kernel(
    const uint2* __restrict__ ebuf, const int* __restrict__ ebase,
    int* __restrict__ deg, float* __restrict__ dinv, int N) {
    __shared__ int cnt[NPB];
    int t = threadIdx.x;
    int n0 = blockIdx.x * NPB;
    int nn = N - n0; if (nn > NPB) nn = NPB;
    cnt[t] = 0;
    __syncthreads();
    int e0 = ebase[blockIdx.x];
    int e1 = ebase[blockIdx.x + 1];
    for (int e = e0 + t; e < e1; e += 256) {
        uint2 sd = ebuf[e];
        atomicAdd(&cnt[(int)sd.y - n0], 1);
    }
    __syncthreads();
    if (t < nn) {
        int c = cnt[t];
        deg[n0 + t] = c;
        dinv[n0 + t] = c > 0 ? rsqrtf((float)c) : 0.0f;
    }
}

// ---------------- rowptr scan ----------------

__global__ void scan1_kernel(const int* __restrict__ deg, int* __restrict__ rowptr,
                             int* __restrict__ bsum, int N) {
    __shared__ int sc[256];
    int t = threadIdx.x;
    int base = blockIdx.x * 1024 + t * 4;
    int d0 = 0, d1 = 0, d2 = 0, d3 = 0;
    if (base + 3 < N) {
        int4 v = *(const int4*)(deg + base);
        d0 = v.x; d1 = v.y; d2 = v.z; d3 = v.w;
    } else {
        if (base     < N) d0 = deg[base];
        if (base + 1 < N) d1 = deg[base + 1];
        if (base + 2 < N) d2 = deg[base + 2];
        if (base + 3 < N) d3 = deg[base + 3];
    }
    int s = d0 + d1 + d2 + d3;
    sc[t] = s;
    __syncthreads();
    for (int off = 1; off < 256; off <<= 1) {
        int v = (t >= off) ? sc[t - off] : 0;
        __syncthreads();
        sc[t] += v;
        __syncthreads();
    }
    int excl = sc[t] - s;
    if (t == 255) bsum[blockIdx.x] = sc[255];
    int dd[4] = {d0, d1, d2, d3};
    int p = excl;
    #pragma unroll
    for (int j = 0; j < 4; j++) {
        int i = base + j;
        if (i < N) rowptr[i] = p;
        p += dd[j];
    }
}

__global__ void scan2_kernel(int* bsum, int nb) {  // nb <= 128
    __shared__ int sc[128];
    int t = threadIdx.x;
    int v = (t < nb) ? bsum[t] : 0;
    sc[t] = v;
    __syncthreads();
    for (int off = 1; off < 128; off <<= 1) {
        int u = (t >= off) ? sc[t - off] : 0;
        __syncthreads();
        sc[t] += u;
        __syncthreads();
    }
    if (t < nb) bsum[t] = sc[t] - v;  // exclusive
}

__global__ void scan3_kernel(int* __restrict__ rowptr, const int* __restrict__ bsum,
                             int N, int E) {
    int t = threadIdx.x, b = blockIdx.x;
    int add = bsum[b];
    int base = b * 1024 + t * 4;
    #pragma unroll
    for (int j = 0; j < 4; j++) {
        int i = base + j;
        if (i < N) rowptr[i] += add;
    }
    if (b == 0 && t == 0) rowptr[N] = E;
}

// ---------------- Phase B: per-bucket fill of csr (writes confined to one L2) ----------------

__global__ __launch_bounds__(256) void bucket_fill_kernel(
    const uint2* __restrict__ ebuf, const int* __restrict__ rowptr,
    int* __restrict__ csr, int N) {
    __shared__ int cnt[NPB];
    __shared__ int rp[NPB];
    int t = threadIdx.x;
    int n0 = blockIdx.x * NPB;
    int nn = N - n0; if (nn > NPB) nn = NPB;
    if (t < nn) { cnt[t] = 0; rp[t] = rowptr[n0 + t]; }
    __syncthreads();
    int e0 = rowptr[n0];
    int e1 = rowptr[n0 + nn];
    for (int e = e0 + t; e < e1; e += 256) {
        uint2 sd = ebuf[e];
        int local = (int)sd.y - n0;
        int p = atomicAdd(&cnt[local], 1);
        csr[rp[local] + p] = (int)sd.x;
    }
}

// ---------------- aggregation + ReLU ----------------
// out[n] = relu( dinv[n] * sum_{s in N(n)} dinv[s] * Yh[s,:] ), Yh bf16 [N,128]

__global__ __launch_bounds__(256) void agg_relu_kernel(
    const uint32* __restrict__ Yh,   // bf16 pairs, row stride 64 dwords
    const int* __restrict__ rowptr, const int* __restrict__ csr,
    const float* __restrict__ dinv, float* __restrict__ out, int N) {
    int node = blockIdx.x * 4 + (threadIdx.x >> 6);
    int lane = threadIdx.x & 63;
    if (node >= N) return;
    int e0 = rowptr[node], e1 = rowptr[node + 1];
    float ax = 0.0f, ay = 0.0f;
    for (int base = e0; base < e1; base += 64) {
        int n = e1 - base;
        if (n > 64) n = 64;
        int s = 0;
        float w = 0.0f;
        if (lane < n) {
            s = csr[base + lane];
            w = dinv[s];
        }
        int nn = (n + 15) & ~15;
        for (int j = 0; j < nn; j += 16) {
            uint32 p[16];
            float wj[16];
            #pragma unroll
            for (int u = 0; u < 16; u++) {
                int sj = __shfl(s, j + u);
                wj[u] = __shfl(w, j + u);
                p[u] = Yh[(size_t)sj * 64 + lane];
            }
            #pragma unroll
            for (int u = 0; u < 16; u++) {
                ax += wj[u] * __uint_as_float(p[u] << 16);
                ay += wj[u] * __uint_as_float(p[u] & 0xffff0000u);
            }
        }
    }
    float wd = dinv[node];
    float2 r;
    r.x = fmaxf(ax * wd, 0.0f);
    r.y = fmaxf(ay * wd, 0.0f);
    *(float2*)(out + (size_t)node * EMB + lane * 2) = r;
}

// ---------------- W split: WhiT/WloT[n][k] = bf16 split of W[k][n] (transposed) ----------------

__global__ void wsplit_kernel(const float* __restrict__ W0, const float* __restrict__ W1,
                              const float* __restrict__ W2,
                              ushort* __restrict__ Whi, ushort* __restrict__ Wlo) {
    const float* W = (blockIdx.x == 0) ? W0 : (blockIdx.x == 1) ? W1 : W2;
    ushort* hiT = Whi + blockIdx.x * EMB * EMB;
    ushort* loT = Wlo + blockIdx.x * EMB * EMB;
    for (int i = threadIdx.x; i < EMB * EMB; i += blockDim.x) {
        int k = i >> 7, n = i & 127;
        float w = W[i];
        uint32 u = __float_as_uint(w);
        ushort hi = (ushort)(u >> 16);                      // RTZ: exact remainder
        float hif = __uint_as_float(u & 0xffff0000u);
        ushort lo = f2bf(w - hif);                          // RNE of remainder
        hiT[n * EMB + k] = hi;
        loT[n * EMB + k] = lo;
    }
}

// ---------------- split-bf16 MFMA GEMM: Yh[M,128](bf16) = A[M,128](fp32) @ W ----------------
// x@w ~= xhi@whi + xhi@wlo + xlo@whi  (xlo@wlo ~ 2^-17 relative, dropped)
// Block: 4 waves; tile 16 rows x 128 cols; wave w -> cols [32w,32w+32).
// B-fragments (8 K-chunks x 2 col-tiles x 16B) live in registers for the whole block.

union FragU { uint32 u[4]; bf16x8 v; };

__global__ __launch_bounds__(256, 2) void gemm_mfma_kernel(
    const float* __restrict__ A, const ushort* __restrict__ WhiT,
    const ushort* __restrict__ WloT, ushort* __restrict__ Yh, int M) {
    __shared__ float As[16][132];   // stride 132: 2-way max bank aliasing on frag reads
    int t = threadIdx.x;
    int wv = t >> 6, lane = t & 63, quad = lane >> 4, l16 = lane & 15;

    // B fragments: lane holds B[k = 32*(kc&3) + 8*quad + j][n = 32*wv + 16*c + l16]
    FragU bfr[8][2];
    #pragma unroll
    for (int kc = 0; kc < 8; kc++) {
        const ushort* srcW = (kc < 4) ? WhiT : WloT;
        int kb = (kc & 3) * 32 + quad * 8;
        #pragma unroll
        for (int c = 0; c < 2; c++) {
            int n = wv * 32 + c * 16 + l16;
            const uint32* p = (const uint32*)(srcW + n * EMB + kb);
            bfr[kc][c].u[0] = p[0];
            bfr[kc][c].u[1] = p[1];
            bfr[kc][c].u[2] = p[2];
            bfr[kc][c].u[3] = p[3];
        }
    }

    int srow = t >> 4, skq = t & 15;
    int ntile = (M + 15) >> 4;
    for (int tile = blockIdx.x; tile < ntile; tile += (int)gridDim.x) {
        int r0 = tile << 4;
        __syncthreads();
        {   // stage 16x128 fp32 rows (coalesced)
            float4 v0 = {0.f, 0.f, 0.f, 0.f}, v1 = v0;
            int row = r0 + srow;
            if (row < M) {
                const float* ga = A + (size_t)row * EMB + skq * 8;
                v0 = *(const float4*)ga;
                v1 = *(const float4*)(ga + 4);
            }
            *(float4*)&As[srow][skq * 8] = v0;
            *(float4*)&As[srow][skq * 8 + 4] = v1;
        }
        __syncthreads();

        // A fragments: lane holds A[m = l16][k = 32*kc + 8*quad + j], split hi/lo
        FragU ah[4], al[4];
        #pragma unroll
        for (int kc = 0; kc < 4; kc++) {
            const float* p = &As[l16][kc * 32 + quad * 8];
            float4 xa = *(const float4*)p;
            float4 xb = *(const float4*)(p + 4);
            uint32 u0 = __float_as_uint(xa.x), u1 = __float_as_uint(xa.y);
            uint32 u2 = __float_as_uint(xa.z), u3 = __float_as_uint(xa.w);
            uint32 u4 = __float_as_uint(xb.x), u5 = __float_as_uint(xb.y);
            uint32 u6 = __float_as_uint(xb.z), u7 = __float_as_uint(xb.w);
            ah[kc].u[0] = pack_hi2(u0, u1);
            ah[kc].u[1] = pack_hi2(u2, u3);
            ah[kc].u[2] = pack_hi2(u4, u5);
            ah[kc].u[3] = pack_hi2(u6, u7);
            float l0 = xa.x - __uint_as_float(u0 & 0xffff0000u);
            float l1 = xa.y - __uint_as_float(u1 & 0xffff0000u);
            float l2 = xa.z - __uint_as_float(u2 & 0xffff0000u);
            float l3 = xa.w - __uint_as_float(u3 & 0xffff0000u);
            float l4 = xb.x - __uint_as_float(u4 & 0xffff0000u);
            float l5 = xb.y - __uint_as_float(u5 & 0xffff0000u);
            float l6 = xb.z - __uint_as_float(u6 & 0xffff0000u);
            float l7 = xb.w - __uint_as_float(u7 & 0xffff0000u);
            al[kc].u[0] = pack_hi2(__float_as_uint(l0), __float_as_uint(l1));
            al[kc].u[1] = pack_hi2(__float_as_uint(l2), __float_as_uint(l3));
            al[kc].u[2] = pack_hi2(__float_as_uint(l4), __float_as_uint(l5));
            al[kc].u[3] = pack_hi2(__float_as_uint(l6), __float_as_uint(l7));
        }

        f32x4 acc0 = {0.f, 0.f, 0.f, 0.f};
        f32x4 acc1 = {0.f, 0.f, 0.f, 0.f};
        #pragma unroll
        for (int kc = 0; kc < 4; kc++) {   // xhi @ whi
            acc0 = __builtin_amdgcn_mfma_f32_16x16x32_bf16(ah[kc].v, bfr[kc][0].v, acc0, 0, 0, 0);
            acc1 = __builtin_amdgcn_mfma_f32_16x16x32_bf16(ah[kc].v, bfr[kc][1].v, acc1, 0, 0, 0);
        }
        #pragma unroll
        for (int kc = 0; kc < 4; kc++) {   // xhi @ wlo
            acc0 = __builtin_amdgcn_mfma_f32_16x16x32_bf16(ah[kc].v, bfr[kc + 4][0].v, acc0, 0, 0, 0);
            acc1 = __builtin_amdgcn_mfma_f32_16x16x32_bf16(ah[kc].v, bfr[kc + 4][1].v, acc1, 0, 0, 0);
        }
        #pragma unroll
        for (int kc = 0; kc < 4; kc++) {   // xlo @ whi
            acc0 = __builtin_amdgcn_mfma_f32_16x16x32_bf16(al[kc].v, bfr[kc][0].v, acc0, 0, 0, 0);
            acc1 = __builtin_amdgcn_mfma_f32_16x16x32_bf16(al[kc].v, bfr[kc][1].v, acc1, 0, 0, 0);
        }

        // C/D layout: col = l16, row = quad*4 + reg  [m89-verified]
        int colb = wv * 32 + l16;
        #pragma unroll
        for (int r = 0; r < 4; r++) {
            int row = r0 + quad * 4 + r;
            if (row < M) {
                Yh[(size_t)row * EMB + colb]      = f2bf(acc0[r]);
                Yh[(size_t)row * EMB + colb + 16] = f2bf(acc1[r]);
            }
        }
    }
}

// ---------------- launch ----------------

extern "C" void kernel_launch(void* const* d_in, const int* in_sizes, int n_in,
                              void* d_out, int out_size, void* d_ws, size_t ws_size,
                              hipStream_t stream) {
    (void)n_in; (void)out_size; (void)ws_size;
    const float* Gu = (const float*)d_in[0];
    const float* Gi = (const float*)d_in[1];
    const float* W0 = (const float*)d_in[2];
    const float* W1 = (const float*)d_in[3];
    const float* W2 = (const float*)d_in[4];
    const int* ei = (const int*)d_in[5];

    int nu = in_sizes[0] / EMB;          // 60000
    int ni = in_sizes[1] / EMB;          // 40000
    int N = nu + ni;                     // 100000
    int E = in_sizes[5] / 2;             // 2000000
    const int* src = ei;
    const int* dst = ei + E;
    int NB = (N + NPB - 1) / NPB;        // 391

    // workspace layout
    ushort* Yh      = (ushort*)d_ws;                   // N*128 bf16 = 25.6 MB
    uint2* ebuf     = (uint2*)(Yh + (size_t)N * EMB);  // E pairs = 16 MB
    int* deg        = (int*)(ebuf + (size_t)E);        // N
    int* rowptr     = deg + N;                         // N+1
    float* dinv     = (float*)(rowptr + N + 1);        // N
    int* csr        = (int*)(dinv + N);                // E
    int* bucket_cnt = csr + E;                         // NB
    int* ebase      = bucket_cnt + NB;                 // NB+1
    int* gcursor    = ebase + NB + 1;                  // NB
    int* bsum       = gcursor + NB;                    // <=128
    ushort* WhiT    = (ushort*)(bsum + 128);           // 3*128*128 bf16
    ushort* WloT    = WhiT + 3 * EMB * EMB;            // 3*128*128 bf16
    float* X        = (float*)d_out;                   // fp32 layer output + final

    hipMemsetAsync(bucket_cnt, 0, sizeof(int) * (size_t)NB, stream);

    wsplit_kernel<<<3, 256, 0, stream>>>(W0, W1, W2, WhiT, WloT);

    int ecb = (E + CHUNK - 1) / CHUNK;                 // 489
    bucket_count_kernel<<<ecb, 256, 0, stream>>>(dst, bucket_cnt, E, NB);
    bucket_scan_kernel<<<1, 512, 0, stream>>>(bucket_cnt, ebase, gcursor, NB, E);
    bucket_scatter_kernel<<<ecb, 256, 0, stream>>>(src, dst, gcursor, ebuf, E, NB);
    bucket_deg_kernel<<<NB, 256, 0, stream>>>(ebuf, ebase, deg, dinv, N);
    int nb = (N + 1023) / 1024;                        // 98
    scan1_kernel<<<nb, 256, 0, stream>>>(deg, rowptr, bsum, N);
    scan2_kernel<<<1, 128, 0, stream>>>(bsum, nb);
    scan3_kernel<<<nb, 256, 0, stream>>>(rowptr, bsum, N, E);
    bucket_fill_kernel<<<NB, 256, 0, stream>>>(ebuf, rowptr, csr, N);

    int aggBlocks = (N + 3) / 4;
    const int GB = 512;                                // gemm grid (2 blocks/CU)

    // layer 1: y = concat(Gu,Gi) @ W0 (bf16 out), x = relu(agg(y))
    gemm_mfma_kernel<<<GB, 256, 0, stream>>>(Gu, WhiT, WloT, Yh, nu);
    gemm_mfma_kernel<<<GB, 256, 0, stream>>>(Gi, WhiT, WloT, Yh + (size_t)nu * EMB, ni);
    agg_relu_kernel<<<aggBlocks, 256, 0, stream>>>((const uint32*)Yh, rowptr, csr, dinv, X, N);
    // layer 2
    gemm_mfma_kernel<<<GB, 256, 0, stream>>>(X, WhiT + EMB * EMB, WloT + EMB * EMB, Yh, N);
    agg_relu_kernel<<<aggBlocks, 256, 0, stream>>>((const uint32*)Yh, rowptr, csr, dinv, X, N);
    // layer 3
    gemm_mfma_kernel<<<GB, 256, 0, stream>>>(X, WhiT + 2 * EMB * EMB, WloT + 2 * EMB * EMB, Yh, N);
    agg_relu_kernel<<<aggBlocks, 256, 0, stream>>>((const uint32*)Yh, rowptr, csr, dinv, X, N);
}